// Round 6
// baseline (193.530 us; speedup 1.0000x reference)
//
#include <hip/hip_runtime.h>

typedef __bf16 bf16;
typedef __bf16 bf16x8 __attribute__((ext_vector_type(8)));
typedef __bf16 bf16x4 __attribute__((ext_vector_type(4)));
typedef float f32x4 __attribute__((ext_vector_type(4)));
typedef float f32x16 __attribute__((ext_vector_type(16)));

#define MFMA16(a, b, c) __builtin_amdgcn_mfma_f32_16x16x32_bf16(a, b, c, 0, 0, 0)
#define MFMA32(a, b, c) __builtin_amdgcn_mfma_f32_32x32x16_bf16(a, b, c, 0, 0, 0)

// scale * log2(e) — folded into Q in GEMM1 epilogue (f32)
#define CS 0.18033688011112042f

// async global->LDS, 16B per lane; LDS dest must be lane-linear per wave.
__device__ __forceinline__ void load_lds16(const bf16* g, bf16* l) {
    __builtin_amdgcn_global_load_lds(
        (const __attribute__((address_space(1))) unsigned int*)g,
        (__attribute__((address_space(3))) unsigned int*)l, 16, 0, 0);
}

__device__ __forceinline__ bf16x4 shfl_xor32_b64(bf16x4 v) {
    union { bf16x4 b; int i[2]; } u;
    u.b = v;
    u.i[0] = __shfl_xor(u.i[0], 32, 64);
    u.i[1] = __shfl_xor(u.i[1], 32, 64);
    return u.b;
}

// PV B-operand fragment for one 16-kv window from C-layout P registers.
// j=0..3 slots: h==0 ? plo(own) : phi(other half); j=4..7: h==0 ? plo(other) : phi(own).
// Proven (rounds 2-4). No permlane builtins.
__device__ __forceinline__ bf16x8 build_bfrag(bf16x4 plo, bf16x4 phi, int h) {
    bf16x4 xlo = shfl_xor32_b64(plo);
    bf16x4 xhi = shfl_xor32_b64(phi);
    bf16x4 lo4 = h ? xhi : plo;
    bf16x4 hi4 = h ? phi : xlo;
    bf16x8 bb;
#pragma unroll
    for (int i = 0; i < 4; ++i) { bb[i] = lo4[i]; bb[4 + i] = hi4[i]; }
    return bb;
}

// ---------------------------------------------------------------------------
// f32 -> bf16 bulk convert (n divisible by 4).
// ---------------------------------------------------------------------------
__global__ __launch_bounds__(256) void f32_to_bf16_kernel(const float* __restrict__ in,
                                                          bf16* __restrict__ out, int n) {
    int i = (blockIdx.x * 256 + threadIdx.x) * 4;
    if (i < n) {
        float4 v = *(const float4*)&in[i];
        bf16x4 o = {(bf16)v.x, (bf16)v.y, (bf16)v.z, (bf16)v.w};
        *(bf16x4*)&out[i] = o;
    }
}

// ---------------------------------------------------------------------------
// f32 [R][C] -> bf16 [C][R] transpose, 32x32 LDS tiles.
// ---------------------------------------------------------------------------
__global__ __launch_bounds__(256) void transpose_f2b(const float* __restrict__ in,
                                                     bf16* __restrict__ out,
                                                     int R, int C) {
    __shared__ float tile[32][33];
    int tx = threadIdx.x & 31, ty = threadIdx.x >> 5;
    int c0 = blockIdx.x * 32, r0 = blockIdx.y * 32;
#pragma unroll
    for (int i = ty; i < 32; i += 8)
        tile[i][tx] = in[(size_t)(r0 + i) * C + c0 + tx];
    __syncthreads();
#pragma unroll
    for (int i = ty; i < 32; i += 8)
        out[(size_t)(c0 + i) * R + r0 + tx] = (bf16)tile[tx][i];
}

// ---------------------------------------------------------------------------
// V slice of qkv (bf16) -> vt[bh][64][2048]  (vt[bh][d][n] = V[b][n][h][d])
// ---------------------------------------------------------------------------
__global__ __launch_bounds__(256) void transpose_v_kernel(const bf16* __restrict__ qkv,
                                                          bf16* __restrict__ vt) {
    __shared__ bf16 tile[32][33];
    int tx = threadIdx.x & 31, ty = threadIdx.x >> 5;
    int bh = blockIdx.z, b = bh >> 3, h = bh & 7;
    int n0 = blockIdx.x * 32, d0 = blockIdx.y * 32;
#pragma unroll
    for (int i = ty; i < 32; i += 8)
        tile[i][tx] = qkv[(size_t)(b * 2048 + n0 + i) * 1536 + 1024 + h * 64 + d0 + tx];
    __syncthreads();
#pragma unroll
    for (int i = ty; i < 32; i += 8)
        vt[(size_t)(bh * 64 + d0 + i) * 2048 + n0 + tx] = tile[tx][i];
}

// ---------------------------------------------------------------------------
// C[M][N] = A[M][K] @ Bt[N][K]^T, bf16 in, fp32 acc. BM=MT*32, BN=128, BK=64.
// global_load_lds staging, XOR chunk swizzle -> conflict-free b128 frags.
// MODE 1: cols<512 scaled by CS (Q pre-scale), bf16 out. MODE 2: +bias, f32.
// ---------------------------------------------------------------------------
template <int MT, int MODE, typename OutT>
__global__ __launch_bounds__(256, 4) void gemm_bt_kernel(const bf16* __restrict__ A,
                                                         const bf16* __restrict__ Bt,
                                                         const float* __restrict__ bias,
                                                         OutT* __restrict__ C,
                                                         int M, int N, int K) {
    const int BM = MT * 32;
    __shared__ bf16 As[BM * 64];
    __shared__ bf16 Bs[128 * 64];
    int t = threadIdx.x;
    int lane = t & 63, w = t >> 6;
    int wr = w >> 1, wc = w & 1;
    int quad = lane >> 4, r16 = lane & 15;
    int m0 = blockIdx.y * BM, n0 = blockIdx.x * 128;

    const f32x4 fzero = {0.f, 0.f, 0.f, 0.f};
    f32x4 acc[MT][4];
#pragma unroll
    for (int i = 0; i < MT; ++i)
#pragma unroll
        for (int j = 0; j < 4; ++j) acc[i][j] = fzero;

    for (int k0 = 0; k0 < K; k0 += 64) {
        __syncthreads();
#pragma unroll
        for (int ci = t; ci < BM * 8; ci += 256) {
            int row = ci >> 3, cp = ci & 7;
            int cc = cp ^ (row & 7);
            load_lds16(&A[(size_t)(m0 + row) * K + k0 + cc * 8], &As[ci * 8]);
        }
#pragma unroll
        for (int ci = t; ci < 1024; ci += 256) {
            int row = ci >> 3, cp = ci & 7;
            int cc = cp ^ (row & 7);
            load_lds16(&Bt[(size_t)(n0 + row) * K + k0 + cc * 8], &Bs[ci * 8]);
        }
        __syncthreads();
#pragma unroll
        for (int ks = 0; ks < 2; ++ks) {
            bf16x8 af[MT], bfr[4];
            int cp = (ks * 4 + quad) ^ (r16 & 7);
#pragma unroll
            for (int mt = 0; mt < MT; ++mt)
                af[mt] = *(const bf16x8*)&As[(wr * (BM / 2) + mt * 16 + r16) * 64 + cp * 8];
#pragma unroll
            for (int nt = 0; nt < 4; ++nt)
                bfr[nt] = *(const bf16x8*)&Bs[(wc * 64 + nt * 16 + r16) * 64 + cp * 8];
#pragma unroll
            for (int mt = 0; mt < MT; ++mt)
#pragma unroll
                for (int nt = 0; nt < 4; ++nt)
                    acc[mt][nt] = MFMA16(af[mt], bfr[nt], acc[mt][nt]);
        }
    }
    // C/D layout: col = lane&15 (n), row = quad*4+reg (m)
#pragma unroll
    for (int mt = 0; mt < MT; ++mt)
#pragma unroll
        for (int nt = 0; nt < 4; ++nt)
#pragma unroll
            for (int r = 0; r < 4; ++r) {
                int row = m0 + wr * (BM / 2) + mt * 16 + quad * 4 + r;
                int col = n0 + wc * 64 + nt * 16 + r16;
                float v = acc[mt][nt][r];
                if (MODE == 1 && n0 < 512) v *= CS;  // pre-scale Q (f32)
                if (MODE == 2) v += bias[col];
                C[(size_t)row * N + col] = (OutT)v;
            }
}

// ---------------------------------------------------------------------------
// Flash attention, split-kv. Block = 4 waves, q-tile 64: waves {0,1} = kv
// half 0, waves {2,3} = kv half 1; wq = w&1 picks the 32-q subtile. Each
// group streams its kv half through its own 16KB LDS buffer (stage ->
// barrier -> compute, proven 2-barrier structure). No-max softmax (Q
// pre-scaled by CS, P = exp2(S)); l on the MFMA pipe (ones trick). Partial
// (O_unnorm, l) merged through LDS at the end (no-max => plain add).
// Grid 1024 blocks -> ~4 blocks/CU.
// ---------------------------------------------------------------------------
__global__ __launch_bounds__(256, 2) void attn_kernel(const bf16* __restrict__ qkv,
                                                      const bf16* __restrict__ vt,
                                                      bf16* __restrict__ out) {
    __shared__ bf16 smem[16384];   // [g][Ks 4096 | Vs 4096], 32KB

    int t = threadIdx.x;
    int lane = t & 63, w = t >> 6;
    int h = lane >> 5, q = lane & 31;
    int g = w >> 1, wq = w & 1;
    int tt = t & 127;              // thread within group
    int bh = blockIdx.y, b = bh >> 3, hd = bh & 7;
    int qb = blockIdx.x * 64;      // block q base
    int qrow = qb + wq * 32 + q;

    // Q fragment (B-operand of S^T): lane holds Q[qrow][d = s*16 + h*8 + j]
    bf16x8 qf[4];
    {
        size_t qoff = (size_t)(b * 2048 + qrow) * 1536 + hd * 64;
#pragma unroll
        for (int s = 0; s < 4; ++s)
            qf[s] = *(const bf16x8*)&qkv[qoff + s * 16 + h * 8];
    }
    bf16x8 ones;
#pragma unroll
    for (int i = 0; i < 8; ++i) ones[i] = (bf16)1.0f;

    f32x16 o_acc[2], lacc;
#pragma unroll
    for (int i = 0; i < 16; ++i) { o_acc[0][i] = 0.f; o_acc[1][i] = 0.f; lacc[i] = 0.f; }

    bf16* Ks = &smem[g * 8192];
    bf16* Vs = Ks + 4096;

    for (int it = 0; it < 16; ++it) {
        int kv0 = g * 1024 + it * 64;
        __syncthreads();           // prev compute's LDS reads done (all waves)
#pragma unroll
        for (int rdd = 0; rdd < 4; ++rdd) {   // K tile [64][64]: 512 chunks
            int ci = rdd * 128 + tt;
            int row = ci >> 3, cp = ci & 7;
            int cc = cp ^ (row & 7);
            load_lds16(&qkv[(size_t)(b * 2048 + kv0 + row) * 1536 + 512 + hd * 64 + cc * 8],
                       &Ks[ci * 8]);
        }
#pragma unroll
        for (int rdd = 0; rdd < 4; ++rdd) {   // V^T tile [64][64]: 512 chunks
            int ci = rdd * 128 + tt;
            int row = ci >> 3, cp = ci & 7;
            int cc = cp ^ (row & 7);
            load_lds16(&vt[(size_t)(bh * 64 + row) * 2048 + kv0 + cc * 8], &Vs[ci * 8]);
        }
        __syncthreads();           // all stage loads drained (vmcnt) + visible

        f32x16 sacc[2];
#pragma unroll
        for (int kb = 0; kb < 2; ++kb)
#pragma unroll
            for (int i = 0; i < 16; ++i) sacc[kb][i] = 0.f;

        // S^T = K.Q^T (pre-scaled): rows kv-local = kb*32+q, cols q'
#pragma unroll
        for (int kb = 0; kb < 2; ++kb) {
            int m = kb * 32 + q;
#pragma unroll
            for (int s = 0; s < 4; ++s) {
                int cp = (s * 2 + h) ^ (q & 7);   // m&7 == q&7
                bf16x8 kf = *(const bf16x8*)&Ks[m * 64 + cp * 8];
                sacc[kb] = MFMA32(kf, qf[s], sacc[kb]);
            }
        }

        // P = exp2(S); build PV B-operand frags in-register (shfl path)
        bf16x8 bfr[4];
#pragma unroll
        for (int kb = 0; kb < 2; ++kb) {
            bf16x4 pk[4];
#pragma unroll
            for (int g8 = 0; g8 < 4; ++g8)
#pragma unroll
                for (int i = 0; i < 4; ++i)
                    pk[g8][i] = (bf16)exp2f(sacc[kb][4 * g8 + i]);
#pragma unroll
            for (int wi = 0; wi < 2; ++wi)
                bfr[kb * 2 + wi] = build_bfrag(pk[2 * wi], pk[2 * wi + 1], h);
        }

        // l accumulation on MFMA pipe: C row 0 = sum_kv P per q col
#pragma unroll
        for (int j = 0; j < 4; ++j) lacc = MFMA32(ones, bfr[j], lacc);

        // O^T += V^T . P^T
#pragma unroll
        for (int kstep = 0; kstep < 4; ++kstep)
#pragma unroll
            for (int db = 0; db < 2; ++db) {
                int d = db * 32 + q;
                int cp = (kstep * 2 + h) ^ (q & 7);   // d&7 == q&7
                bf16x8 vf = *(const bf16x8*)&Vs[d * 64 + cp * 8];
                o_acc[db] = MFMA32(vf, bfr[kstep], o_acc[db]);
            }
    }

    // own partial l for this lane's q column (valid all lanes)
    float l_own = __shfl(lacc[0], q, 64);

    // ---- merge the two kv halves through LDS ----
    __syncthreads();
    float* Of = (float*)smem;            // [2 wq][64 d][32 q] f32 = 16KB
    float* Lf = (float*)(smem + 8192);   // [2 wq][32 q] f32
    bf16*  Ot = smem + 8320;             // [64 q][72] bf16

    if (g == 1) {
#pragma unroll
        for (int db = 0; db < 2; ++db)
#pragma unroll
            for (int g8 = 0; g8 < 4; ++g8)
#pragma unroll
                for (int i = 0; i < 4; ++i)
                    Of[(wq * 64 + db * 32 + g8 * 8 + h * 4 + i) * 32 + q] =
                        o_acc[db][g8 * 4 + i];
        if (h == 0) Lf[wq * 32 + q] = l_own;
    }
    __syncthreads();
    if (g == 0) {
        float linv = 1.f / (l_own + Lf[wq * 32 + q]);
#pragma unroll
        for (int db = 0; db < 2; ++db)
#pragma unroll
            for (int g8 = 0; g8 < 4; ++g8) {
                bf16x4 ov;
#pragma unroll
                for (int i = 0; i < 4; ++i)
                    ov[i] = (bf16)((o_acc[db][g8 * 4 + i] +
                                    Of[(wq * 64 + db * 32 + g8 * 8 + h * 4 + i) * 32 + q]) *
                                   linv);
                *(bf16x4*)&Ot[(wq * 32 + q) * 72 + db * 32 + g8 * 8 + h * 4] = ov;
            }
    }
    __syncthreads();
    // coalesced write: 64 rows x 64 cols bf16, 512 b128-chunks, 2 per thread
#pragma unroll
    for (int rnd = 0; rnd < 2; ++rnd) {
        int idx = rnd * 256 + t;
        int row = idx >> 3, col = (idx & 7) * 8;
        bf16x8 ov = *(const bf16x8*)&Ot[row * 72 + col];
        *(bf16x8*)&out[(size_t)(b * 2048 + qb + row) * 512 + hd * 64 + col] = ov;
    }
}

// ---------------------------------------------------------------------------
extern "C" void kernel_launch(void* const* d_in, const int* in_sizes, int n_in,
                              void* d_out, int out_size, void* d_ws, size_t ws_size,
                              hipStream_t stream) {
    const float* x     = (const float*)d_in[0];   // [4*2048][512] f32
    const float* w_qkv = (const float*)d_in[1];   // [512][1536]   f32
    const float* w_out = (const float*)d_in[2];   // [512][512]    f32
    const float* b_out = (const float*)d_in[3];   // [512]         f32
    float* out = (float*)d_out;                   // [4*2048][512] f32

    char* ws = (char*)d_ws;
    size_t off = 0;
    bf16* xb    = (bf16*)(ws + off); off += (size_t)8192 * 512 * 2;        // 8 MB
    bf16* wqkvT = (bf16*)(ws + off); off += (size_t)1536 * 512 * 2;        // 1.5 MB
    bf16* woutT = (bf16*)(ws + off); off += (size_t)512 * 512 * 2;         // 0.5 MB
    bf16* qkv   = (bf16*)(ws + off); off += (size_t)8192 * 1536 * 2;       // 24 MB
    bf16* vt    = (bf16*)(ws + off); off += (size_t)32 * 64 * 2048 * 2;    // 8 MB
    bf16* attn  = (bf16*)(ws + off);                                       // 8 MB

    f32_to_bf16_kernel<<<4096, 256, 0, stream>>>(x, xb, 8192 * 512);
    transpose_f2b<<<dim3(48, 16), 256, 0, stream>>>(w_qkv, wqkvT, 512, 1536);
    transpose_f2b<<<dim3(16, 16), 256, 0, stream>>>(w_out, woutT, 512, 512);
    // QKV GEMM, BM=64: Q cols pre-scaled by CS
    gemm_bt_kernel<2, 1, bf16><<<dim3(12, 128), 256, 0, stream>>>(
        xb, wqkvT, nullptr, qkv, 8192, 1536, 512);
    transpose_v_kernel<<<dim3(64, 2, 32), 256, 0, stream>>>(qkv, vt);
    attn_kernel<<<dim3(32, 32), 256, 0, stream>>>(qkv, vt, attn);
    // out proj, BM=32 (grid 1024 -> 4 blocks/CU), +bias, f32 out
    gemm_bt_kernel<1, 2, float><<<dim3(4, 256), 256, 0, stream>>>(
        attn, woutT, b_out, out, 8192, 512, 512);
}

// Round 7
// 183.866 us; speedup vs baseline: 1.0526x; 1.0526x over previous
//
#include <hip/hip_runtime.h>

typedef __bf16 bf16;
typedef __bf16 bf16x8 __attribute__((ext_vector_type(8)));
typedef __bf16 bf16x4 __attribute__((ext_vector_type(4)));
typedef float f32x4 __attribute__((ext_vector_type(4)));
typedef float f32x16 __attribute__((ext_vector_type(16)));

#define MFMA16(a, b, c) __builtin_amdgcn_mfma_f32_16x16x32_bf16(a, b, c, 0, 0, 0)
#define MFMA32(a, b, c) __builtin_amdgcn_mfma_f32_32x32x16_bf16(a, b, c, 0, 0, 0)

// scale * log2(e) — folded into Q in GEMM1 epilogue (f32)
#define CS 0.18033688011112042f

// raw v_exp_f32 (no libm denormal fixup); args bounded (~|S|<60) so safe
#if __has_builtin(__builtin_amdgcn_exp2f)
#define EXP2(x) __builtin_amdgcn_exp2f(x)
#else
#define EXP2(x) exp2f(x)
#endif

// async global->LDS, 16B per lane; LDS dest must be lane-linear per wave.
__device__ __forceinline__ void load_lds16(const bf16* g, bf16* l) {
    __builtin_amdgcn_global_load_lds(
        (const __attribute__((address_space(1))) unsigned int*)g,
        (__attribute__((address_space(3))) unsigned int*)l, 16, 0, 0);
}

__device__ __forceinline__ bf16x4 shfl_xor32_b64(bf16x4 v) {
    union { bf16x4 b; int i[2]; } u;
    u.b = v;
    u.i[0] = __shfl_xor(u.i[0], 32, 64);
    u.i[1] = __shfl_xor(u.i[1], 32, 64);
    return u.b;
}

// PV B-operand fragment for one 16-kv window from C-layout P registers.
// Proven (rounds 2-4,6). No permlane builtins.
__device__ __forceinline__ bf16x8 build_bfrag(bf16x4 plo, bf16x4 phi, int h) {
    bf16x4 xlo = shfl_xor32_b64(plo);
    bf16x4 xhi = shfl_xor32_b64(phi);
    bf16x4 lo4 = h ? xhi : plo;
    bf16x4 hi4 = h ? phi : xlo;
    bf16x8 bb;
#pragma unroll
    for (int i = 0; i < 4; ++i) { bb[i] = lo4[i]; bb[4 + i] = hi4[i]; }
    return bb;
}

// ---------------------------------------------------------------------------
// f32 -> bf16 bulk convert (n divisible by 4).
// ---------------------------------------------------------------------------
__global__ __launch_bounds__(256) void f32_to_bf16_kernel(const float* __restrict__ in,
                                                          bf16* __restrict__ out, int n) {
    int i = (blockIdx.x * 256 + threadIdx.x) * 4;
    if (i < n) {
        float4 v = *(const float4*)&in[i];
        bf16x4 o = {(bf16)v.x, (bf16)v.y, (bf16)v.z, (bf16)v.w};
        *(bf16x4*)&out[i] = o;
    }
}

// ---------------------------------------------------------------------------
// f32 [R][C] -> bf16 [C][R] transpose, 32x32 LDS tiles.
// ---------------------------------------------------------------------------
__global__ __launch_bounds__(256) void transpose_f2b(const float* __restrict__ in,
                                                     bf16* __restrict__ out,
                                                     int R, int C) {
    __shared__ float tile[32][33];
    int tx = threadIdx.x & 31, ty = threadIdx.x >> 5;
    int c0 = blockIdx.x * 32, r0 = blockIdx.y * 32;
#pragma unroll
    for (int i = ty; i < 32; i += 8)
        tile[i][tx] = in[(size_t)(r0 + i) * C + c0 + tx];
    __syncthreads();
#pragma unroll
    for (int i = ty; i < 32; i += 8)
        out[(size_t)(c0 + i) * R + r0 + tx] = (bf16)tile[tx][i];
}

// ---------------------------------------------------------------------------
// V slice of qkv (bf16) -> vt[bh][64][2048]  (vt[bh][d][n] = V[b][n][h][d])
// ---------------------------------------------------------------------------
__global__ __launch_bounds__(256) void transpose_v_kernel(const bf16* __restrict__ qkv,
                                                          bf16* __restrict__ vt) {
    __shared__ bf16 tile[32][33];
    int tx = threadIdx.x & 31, ty = threadIdx.x >> 5;
    int bh = blockIdx.z, b = bh >> 3, h = bh & 7;
    int n0 = blockIdx.x * 32, d0 = blockIdx.y * 32;
#pragma unroll
    for (int i = ty; i < 32; i += 8)
        tile[i][tx] = qkv[(size_t)(b * 2048 + n0 + i) * 1536 + 1024 + h * 64 + d0 + tx];
    __syncthreads();
#pragma unroll
    for (int i = ty; i < 32; i += 8)
        vt[(size_t)(bh * 64 + d0 + i) * 2048 + n0 + tx] = tile[tx][i];
}

// ---------------------------------------------------------------------------
// C[M][N] = A[M][K] @ Bt[N][K]^T, bf16 in, fp32 acc. BM=MT*32, BN=128, BK=64.
// Staging pointers precomputed once, advanced by 64 elems (128B) per k-iter.
// XOR chunk swizzle -> conflict-free b128 frags.
// MODE 1: cols<512 scaled by CS (Q pre-scale), bf16 out. MODE 2: +bias, f32.
// ---------------------------------------------------------------------------
template <int MT, int MODE, typename OutT>
__global__ __launch_bounds__(256, 4) void gemm_bt_kernel(const bf16* __restrict__ A,
                                                         const bf16* __restrict__ Bt,
                                                         const float* __restrict__ bias,
                                                         OutT* __restrict__ C,
                                                         int M, int N, int K) {
    const int BM = MT * 32;
    __shared__ bf16 As[BM * 64];
    __shared__ bf16 Bs[128 * 64];
    int t = threadIdx.x;
    int lane = t & 63, w = t >> 6;
    int wr = w >> 1, wc = w & 1;
    int quad = lane >> 4, r16 = lane & 15;
    int m0 = blockIdx.y * BM, n0 = blockIdx.x * 128;

    const f32x4 fzero = {0.f, 0.f, 0.f, 0.f};
    f32x4 acc[MT][4];
#pragma unroll
    for (int i = 0; i < MT; ++i)
#pragma unroll
        for (int j = 0; j < 4; ++j) acc[i][j] = fzero;

    // precompute staging pointers (iter 0), advance by +64 per k-iter
    const bf16* ap[MT]; bf16* ad[MT];
    const bf16* bp[4];  bf16* bd[4];
#pragma unroll
    for (int i = 0; i < MT; ++i) {
        int ci = i * 256 + t;
        int row = ci >> 3, cp = ci & 7, cc = cp ^ (row & 7);
        ap[i] = &A[(size_t)(m0 + row) * K + cc * 8];
        ad[i] = &As[ci * 8];
    }
#pragma unroll
    for (int i = 0; i < 4; ++i) {
        int ci = i * 256 + t;
        int row = ci >> 3, cp = ci & 7, cc = cp ^ (row & 7);
        bp[i] = &Bt[(size_t)(n0 + row) * K + cc * 8];
        bd[i] = &Bs[ci * 8];
    }

    for (int k0 = 0; k0 < K; k0 += 64) {
        __syncthreads();
#pragma unroll
        for (int i = 0; i < MT; ++i) { load_lds16(ap[i], ad[i]); ap[i] += 64; }
#pragma unroll
        for (int i = 0; i < 4; ++i) { load_lds16(bp[i], bd[i]); bp[i] += 64; }
        __syncthreads();
#pragma unroll
        for (int ks = 0; ks < 2; ++ks) {
            bf16x8 af[MT], bfr[4];
            int cp = (ks * 4 + quad) ^ (r16 & 7);
#pragma unroll
            for (int mt = 0; mt < MT; ++mt)
                af[mt] = *(const bf16x8*)&As[(wr * (BM / 2) + mt * 16 + r16) * 64 + cp * 8];
#pragma unroll
            for (int nt = 0; nt < 4; ++nt)
                bfr[nt] = *(const bf16x8*)&Bs[(wc * 64 + nt * 16 + r16) * 64 + cp * 8];
#pragma unroll
            for (int mt = 0; mt < MT; ++mt)
#pragma unroll
                for (int nt = 0; nt < 4; ++nt)
                    acc[mt][nt] = MFMA16(af[mt], bfr[nt], acc[mt][nt]);
        }
    }
    // C/D layout: col = lane&15 (n), row = quad*4+reg (m)
#pragma unroll
    for (int mt = 0; mt < MT; ++mt)
#pragma unroll
        for (int nt = 0; nt < 4; ++nt)
#pragma unroll
            for (int r = 0; r < 4; ++r) {
                int row = m0 + wr * (BM / 2) + mt * 16 + quad * 4 + r;
                int col = n0 + wc * 64 + nt * 16 + r16;
                float v = acc[mt][nt][r];
                if (MODE == 1 && n0 < 512) v *= CS;  // pre-scale Q (f32)
                if (MODE == 2) v += bias[col];
                C[(size_t)row * N + col] = (OutT)v;
            }
}

// ---------------------------------------------------------------------------
// Flash attention, split-kv (round-6 structure, replay-proven). Block = 4
// waves, q-tile 64: wave-group g = kv half, wq = q subtile. Stage->barrier->
// compute; staging pointers advanced by constant stride per iter. No-max
// softmax (Q pre-scaled; P = exp2(S) via raw v_exp_f32); l via ones-MFMA.
// Partials merged through LDS (plain add).
// ---------------------------------------------------------------------------
__global__ __launch_bounds__(256, 2) void attn_kernel(const bf16* __restrict__ qkv,
                                                      const bf16* __restrict__ vt,
                                                      bf16* __restrict__ out) {
    __shared__ bf16 smem[16384];   // [g][Ks 4096 | Vs 4096], 32KB

    int t = threadIdx.x;
    int lane = t & 63, w = t >> 6;
    int h = lane >> 5, q = lane & 31;
    int g = w >> 1, wq = w & 1;
    int tt = t & 127;              // thread within group
    int bh = blockIdx.y, b = bh >> 3, hd = bh & 7;
    int qb = blockIdx.x * 64;      // block q base
    int qrow = qb + wq * 32 + q;

    // Q fragment (B-operand of S^T): lane holds Q[qrow][d = s*16 + h*8 + j]
    bf16x8 qf[4];
    {
        size_t qoff = (size_t)(b * 2048 + qrow) * 1536 + hd * 64;
#pragma unroll
        for (int s = 0; s < 4; ++s)
            qf[s] = *(const bf16x8*)&qkv[qoff + s * 16 + h * 8];
    }
    bf16x8 ones;
#pragma unroll
    for (int i = 0; i < 8; ++i) ones[i] = (bf16)1.0f;

    f32x16 o_acc[2], lacc;
#pragma unroll
    for (int i = 0; i < 16; ++i) { o_acc[0][i] = 0.f; o_acc[1][i] = 0.f; lacc[i] = 0.f; }

    bf16* Ks = &smem[g * 8192];
    bf16* Vs = Ks + 4096;

    // staging pointers (iter 0 of this group's kv half); constant stride advance
    const bf16* kp[4]; const bf16* vp[4];
    bf16* kd[4]; bf16* vd[4];
#pragma unroll
    for (int rdd = 0; rdd < 4; ++rdd) {
        int ci = rdd * 128 + tt;
        int row = ci >> 3, cp = ci & 7, cc = cp ^ (row & 7);
        kp[rdd] = &qkv[(size_t)(b * 2048 + g * 1024 + row) * 1536 + 512 + hd * 64 + cc * 8];
        kd[rdd] = &Ks[ci * 8];
        vp[rdd] = &vt[(size_t)(bh * 64 + row) * 2048 + g * 1024 + cc * 8];
        vd[rdd] = &Vs[ci * 8];
    }

    for (int it = 0; it < 16; ++it) {
        __syncthreads();           // prev compute's LDS reads done (all waves)
#pragma unroll
        for (int rdd = 0; rdd < 4; ++rdd) {
            load_lds16(kp[rdd], kd[rdd]); kp[rdd] += (size_t)64 * 1536;
            load_lds16(vp[rdd], vd[rdd]); vp[rdd] += 64;
        }
        __syncthreads();           // stage loads drained + visible

        f32x16 sacc[2];
#pragma unroll
        for (int kb = 0; kb < 2; ++kb)
#pragma unroll
            for (int i = 0; i < 16; ++i) sacc[kb][i] = 0.f;

        // S^T = K.Q^T (pre-scaled): rows kv-local = kb*32+q, cols q'
#pragma unroll
        for (int kb = 0; kb < 2; ++kb) {
            int m = kb * 32 + q;
#pragma unroll
            for (int s = 0; s < 4; ++s) {
                int cp = (s * 2 + h) ^ (q & 7);   // m&7 == q&7
                bf16x8 kf = *(const bf16x8*)&Ks[m * 64 + cp * 8];
                sacc[kb] = MFMA32(kf, qf[s], sacc[kb]);
            }
        }

        // P = exp2(S); build PV B-operand frags in-register (shfl path)
        bf16x8 bfr[4];
#pragma unroll
        for (int kb = 0; kb < 2; ++kb) {
            bf16x4 pk[4];
#pragma unroll
            for (int g8 = 0; g8 < 4; ++g8)
#pragma unroll
                for (int i = 0; i < 4; ++i)
                    pk[g8][i] = (bf16)EXP2(sacc[kb][4 * g8 + i]);
#pragma unroll
            for (int wi = 0; wi < 2; ++wi)
                bfr[kb * 2 + wi] = build_bfrag(pk[2 * wi], pk[2 * wi + 1], h);
        }

        // l accumulation on MFMA pipe: C row 0 = sum_kv P per q col
#pragma unroll
        for (int j = 0; j < 4; ++j) lacc = MFMA32(ones, bfr[j], lacc);

        // O^T += V^T . P^T
#pragma unroll
        for (int kstep = 0; kstep < 4; ++kstep)
#pragma unroll
            for (int db = 0; db < 2; ++db) {
                int d = db * 32 + q;
                int cp = (kstep * 2 + h) ^ (q & 7);   // d&7 == q&7
                bf16x8 vf = *(const bf16x8*)&Vs[d * 64 + cp * 8];
                o_acc[db] = MFMA32(vf, bfr[kstep], o_acc[db]);
            }
    }

    // own partial l for this lane's q column (valid all lanes)
    float l_own = __shfl(lacc[0], q, 64);

    // ---- merge the two kv halves through LDS ----
    __syncthreads();
    float* Of = (float*)smem;            // [2 wq][64 d][32 q] f32 = 16KB
    float* Lf = (float*)(smem + 8192);   // [2 wq][32 q] f32
    bf16*  Ot = smem + 8320;             // [64 q][72] bf16

    if (g == 1) {
#pragma unroll
        for (int db = 0; db < 2; ++db)
#pragma unroll
            for (int g8 = 0; g8 < 4; ++g8)
#pragma unroll
                for (int i = 0; i < 4; ++i)
                    Of[(wq * 64 + db * 32 + g8 * 8 + h * 4 + i) * 32 + q] =
                        o_acc[db][g8 * 4 + i];
        if (h == 0) Lf[wq * 32 + q] = l_own;
    }
    __syncthreads();
    if (g == 0) {
        float linv = 1.f / (l_own + Lf[wq * 32 + q]);
#pragma unroll
        for (int db = 0; db < 2; ++db)
#pragma unroll
            for (int g8 = 0; g8 < 4; ++g8) {
                bf16x4 ov;
#pragma unroll
                for (int i = 0; i < 4; ++i)
                    ov[i] = (bf16)((o_acc[db][g8 * 4 + i] +
                                    Of[(wq * 64 + db * 32 + g8 * 8 + h * 4 + i) * 32 + q]) *
                                   linv);
                *(bf16x4*)&Ot[(wq * 32 + q) * 72 + db * 32 + g8 * 8 + h * 4] = ov;
            }
    }
    __syncthreads();
    // coalesced write: 64 rows x 64 cols bf16, 512 b128-chunks, 2 per thread
#pragma unroll
    for (int rnd = 0; rnd < 2; ++rnd) {
        int idx = rnd * 256 + t;
        int row = idx >> 3, col = (idx & 7) * 8;
        bf16x8 ov = *(const bf16x8*)&Ot[row * 72 + col];
        *(bf16x8*)&out[(size_t)(b * 2048 + qb + row) * 512 + hd * 64 + col] = ov;
    }
}

// ---------------------------------------------------------------------------
extern "C" void kernel_launch(void* const* d_in, const int* in_sizes, int n_in,
                              void* d_out, int out_size, void* d_ws, size_t ws_size,
                              hipStream_t stream) {
    const float* x     = (const float*)d_in[0];   // [4*2048][512] f32
    const float* w_qkv = (const float*)d_in[1];   // [512][1536]   f32
    const float* w_out = (const float*)d_in[2];   // [512][512]    f32
    const float* b_out = (const float*)d_in[3];   // [512]         f32
    float* out = (float*)d_out;                   // [4*2048][512] f32

    char* ws = (char*)d_ws;
    size_t off = 0;
    bf16* xb    = (bf16*)(ws + off); off += (size_t)8192 * 512 * 2;        // 8 MB
    bf16* wqkvT = (bf16*)(ws + off); off += (size_t)1536 * 512 * 2;        // 1.5 MB
    bf16* woutT = (bf16*)(ws + off); off += (size_t)512 * 512 * 2;         // 0.5 MB
    bf16* qkv   = (bf16*)(ws + off); off += (size_t)8192 * 1536 * 2;       // 24 MB
    bf16* vt    = (bf16*)(ws + off); off += (size_t)32 * 64 * 2048 * 2;    // 8 MB
    bf16* attn  = (bf16*)(ws + off);                                       // 8 MB

    f32_to_bf16_kernel<<<4096, 256, 0, stream>>>(x, xb, 8192 * 512);
    transpose_f2b<<<dim3(48, 16), 256, 0, stream>>>(w_qkv, wqkvT, 512, 1536);
    transpose_f2b<<<dim3(16, 16), 256, 0, stream>>>(w_out, woutT, 512, 512);
    // QKV GEMM, BM=64: Q cols pre-scaled by CS
    gemm_bt_kernel<2, 1, bf16><<<dim3(12, 128), 256, 0, stream>>>(
        xb, wqkvT, nullptr, qkv, 8192, 1536, 512);
    transpose_v_kernel<<<dim3(64, 2, 32), 256, 0, stream>>>(qkv, vt);
    attn_kernel<<<dim3(32, 32), 256, 0, stream>>>(qkv, vt, attn);
    // out proj, BM=64 (grid 512), +bias, f32 out
    gemm_bt_kernel<2, 2, float><<<dim3(4, 128), 256, 0, stream>>>(
        attn, woutT, b_out, out, 8192, 512, 512);
}

// Round 8
// 170.908 us; speedup vs baseline: 1.1324x; 1.0758x over previous
//
#include <hip/hip_runtime.h>

typedef __bf16 bf16;
typedef __bf16 bf16x8 __attribute__((ext_vector_type(8)));
typedef __bf16 bf16x4 __attribute__((ext_vector_type(4)));
typedef float f32x4 __attribute__((ext_vector_type(4)));
typedef float f32x16 __attribute__((ext_vector_type(16)));

#define MFMA16(a, b, c) __builtin_amdgcn_mfma_f32_16x16x32_bf16(a, b, c, 0, 0, 0)
#define MFMA32(a, b, c) __builtin_amdgcn_mfma_f32_32x32x16_bf16(a, b, c, 0, 0, 0)

// scale * log2(e) — folded into Q in GEMM1 epilogue (f32)
#define CS 0.18033688011112042f

// raw v_exp_f32 (r7-proven); args bounded so denormal fixup not needed
#if __has_builtin(__builtin_amdgcn_exp2f)
#define EXP2(x) __builtin_amdgcn_exp2f(x)
#else
#define EXP2(x) exp2f(x)
#endif

// wave-local wait: vmcnt(0), lgkm/exp ignored (0xF70: lgkm=15, exp=7, vm=0)
#define WAIT_VM0() __builtin_amdgcn_s_waitcnt(0x0F70)

// async global->LDS, 16B per lane; LDS dest must be lane-linear per wave.
__device__ __forceinline__ void load_lds16(const bf16* g, bf16* l) {
    __builtin_amdgcn_global_load_lds(
        (const __attribute__((address_space(1))) unsigned int*)g,
        (__attribute__((address_space(3))) unsigned int*)l, 16, 0, 0);
}

__device__ __forceinline__ bf16x4 shfl_xor32_b64(bf16x4 v) {
    union { bf16x4 b; int i[2]; } u;
    u.b = v;
    u.i[0] = __shfl_xor(u.i[0], 32, 64);
    u.i[1] = __shfl_xor(u.i[1], 32, 64);
    return u.b;
}

// PV B-operand fragment for one 16-kv window from C-layout P registers.
// Proven rounds 2-4, 6, 7.
__device__ __forceinline__ bf16x8 build_bfrag(bf16x4 plo, bf16x4 phi, int h) {
    bf16x4 xlo = shfl_xor32_b64(plo);
    bf16x4 xhi = shfl_xor32_b64(phi);
    bf16x4 lo4 = h ? xhi : plo;
    bf16x4 hi4 = h ? phi : xlo;
    bf16x8 bb;
#pragma unroll
    for (int i = 0; i < 4; ++i) { bb[i] = lo4[i]; bb[4 + i] = hi4[i]; }
    return bb;
}

// ---------------------------------------------------------------------------
// f32 -> bf16 bulk convert (n divisible by 4).
// ---------------------------------------------------------------------------
__global__ __launch_bounds__(256) void f32_to_bf16_kernel(const float* __restrict__ in,
                                                          bf16* __restrict__ out, int n) {
    int i = (blockIdx.x * 256 + threadIdx.x) * 4;
    if (i < n) {
        float4 v = *(const float4*)&in[i];
        bf16x4 o = {(bf16)v.x, (bf16)v.y, (bf16)v.z, (bf16)v.w};
        *(bf16x4*)&out[i] = o;
    }
}

// ---------------------------------------------------------------------------
// f32 [R][C] -> bf16 [C][R] transpose, 32x32 LDS tiles.
// ---------------------------------------------------------------------------
__global__ __launch_bounds__(256) void transpose_f2b(const float* __restrict__ in,
                                                     bf16* __restrict__ out,
                                                     int R, int C) {
    __shared__ float tile[32][33];
    int tx = threadIdx.x & 31, ty = threadIdx.x >> 5;
    int c0 = blockIdx.x * 32, r0 = blockIdx.y * 32;
#pragma unroll
    for (int i = ty; i < 32; i += 8)
        tile[i][tx] = in[(size_t)(r0 + i) * C + c0 + tx];
    __syncthreads();
#pragma unroll
    for (int i = ty; i < 32; i += 8)
        out[(size_t)(c0 + i) * R + r0 + tx] = (bf16)tile[tx][i];
}

// ---------------------------------------------------------------------------
// V slice of qkv (bf16) -> vt[bh][64][2048]  (vt[bh][d][n] = V[b][n][h][d])
// ---------------------------------------------------------------------------
__global__ __launch_bounds__(256) void transpose_v_kernel(const bf16* __restrict__ qkv,
                                                          bf16* __restrict__ vt) {
    __shared__ bf16 tile[32][33];
    int tx = threadIdx.x & 31, ty = threadIdx.x >> 5;
    int bh = blockIdx.z, b = bh >> 3, h = bh & 7;
    int n0 = blockIdx.x * 32, d0 = blockIdx.y * 32;
#pragma unroll
    for (int i = ty; i < 32; i += 8)
        tile[i][tx] = qkv[(size_t)(b * 2048 + n0 + i) * 1536 + 1024 + h * 64 + d0 + tx];
    __syncthreads();
#pragma unroll
    for (int i = ty; i < 32; i += 8)
        vt[(size_t)(bh * 64 + d0 + i) * 2048 + n0 + tx] = tile[tx][i];
}

// ---------------------------------------------------------------------------
// C[M][N] = A[M][K] @ Bt[N][K]^T, bf16 in, fp32 acc. BM=MT*32, BN=128, BK=64.
// Staging pointers precomputed, advanced by 64 elems per k-iter.
// MODE 1: cols<512 scaled by CS (Q pre-scale), bf16 out. MODE 2: +bias, f32.
// MT=4 (128x128, m97 shape) for big GEMM, MT=2 for out-proj.
// ---------------------------------------------------------------------------
template <int MT, int MODE, typename OutT>
__global__ __launch_bounds__(256, (MT == 4) ? 2 : 4)
void gemm_bt_kernel(const bf16* __restrict__ A,
                    const bf16* __restrict__ Bt,
                    const float* __restrict__ bias,
                    OutT* __restrict__ C,
                    int M, int N, int K) {
    const int BM = MT * 32;
    __shared__ bf16 As[BM * 64];
    __shared__ bf16 Bs[128 * 64];
    int t = threadIdx.x;
    int lane = t & 63, w = t >> 6;
    int wr = w >> 1, wc = w & 1;
    int quad = lane >> 4, r16 = lane & 15;
    int m0 = blockIdx.y * BM, n0 = blockIdx.x * 128;

    const f32x4 fzero = {0.f, 0.f, 0.f, 0.f};
    f32x4 acc[MT][4];
#pragma unroll
    for (int i = 0; i < MT; ++i)
#pragma unroll
        for (int j = 0; j < 4; ++j) acc[i][j] = fzero;

    const bf16* ap[MT]; bf16* ad[MT];
    const bf16* bp[4];  bf16* bd[4];
#pragma unroll
    for (int i = 0; i < MT; ++i) {
        int ci = i * 256 + t;
        int row = ci >> 3, cp = ci & 7, cc = cp ^ (row & 7);
        ap[i] = &A[(size_t)(m0 + row) * K + cc * 8];
        ad[i] = &As[ci * 8];
    }
#pragma unroll
    for (int i = 0; i < 4; ++i) {
        int ci = i * 256 + t;
        int row = ci >> 3, cp = ci & 7, cc = cp ^ (row & 7);
        bp[i] = &Bt[(size_t)(n0 + row) * K + cc * 8];
        bd[i] = &Bs[ci * 8];
    }

    for (int k0 = 0; k0 < K; k0 += 64) {
        __syncthreads();
#pragma unroll
        for (int i = 0; i < MT; ++i) { load_lds16(ap[i], ad[i]); ap[i] += 64; }
#pragma unroll
        for (int i = 0; i < 4; ++i) { load_lds16(bp[i], bd[i]); bp[i] += 64; }
        __syncthreads();
#pragma unroll
        for (int ks = 0; ks < 2; ++ks) {
            bf16x8 af[MT], bfr[4];
            int cp = (ks * 4 + quad) ^ (r16 & 7);
#pragma unroll
            for (int mt = 0; mt < MT; ++mt)
                af[mt] = *(const bf16x8*)&As[(wr * (BM / 2) + mt * 16 + r16) * 64 + cp * 8];
#pragma unroll
            for (int nt = 0; nt < 4; ++nt)
                bfr[nt] = *(const bf16x8*)&Bs[(wc * 64 + nt * 16 + r16) * 64 + cp * 8];
#pragma unroll
            for (int mt = 0; mt < MT; ++mt)
#pragma unroll
                for (int nt = 0; nt < 4; ++nt)
                    acc[mt][nt] = MFMA16(af[mt], bfr[nt], acc[mt][nt]);
        }
    }
#pragma unroll
    for (int mt = 0; mt < MT; ++mt)
#pragma unroll
        for (int nt = 0; nt < 4; ++nt)
#pragma unroll
            for (int r = 0; r < 4; ++r) {
                int row = m0 + wr * (BM / 2) + mt * 16 + quad * 4 + r;
                int col = n0 + wc * 64 + nt * 16 + r16;
                float v = acc[mt][nt][r];
                if (MODE == 1 && n0 < 512) v *= CS;
                if (MODE == 2) v += bias[col];
                C[(size_t)row * N + col] = (OutT)v;
            }
}

// ---------------------------------------------------------------------------
// Flash attention v3: barrier-free per-wave streaming.
// Block = 2 waves (128 thr); wave w owns kv half [w*1024, w*1024+1024),
// 32 iters of kv-32, with its OWN 8KB LDS tile (Ks[32][64] + Vs[64][32]) —
// no __syncthreads in the main loop, only a wave-local vmcnt(0) after
// staging. q-tile 64 per wave = 2 subtiles sharing K/V register fragments.
// No-max softmax (Q pre-scaled by CS); l via f32 psum. 2-way merge via LDS.
// Grid (32 qb, 32 bh) = 1024 blocks.
// ---------------------------------------------------------------------------
__global__ __launch_bounds__(128, 2) void attn_kernel(const bf16* __restrict__ qkv,
                                                      const bf16* __restrict__ vt,
                                                      bf16* __restrict__ out) {
    __shared__ __align__(16) char smemraw[18432];
    bf16* stage = (bf16*)smemraw;       // [2 waves][4096 elems] = 16KB

    int t = threadIdx.x;
    int lane = t & 63, w = t >> 6;      // w in {0,1}
    int h = lane >> 5, q = lane & 31;
    int bh = blockIdx.y, b = bh >> 3, hd = bh & 7;
    int qb = blockIdx.x * 64;

    // Q fragments for both subtiles: lane holds Q[qb+sub*32+q][s*16+h*8+j]
    bf16x8 qf[2][4];
#pragma unroll
    for (int sub = 0; sub < 2; ++sub) {
        size_t qoff = (size_t)(b * 2048 + qb + sub * 32 + q) * 1536 + hd * 64;
#pragma unroll
        for (int s = 0; s < 4; ++s)
            qf[sub][s] = *(const bf16x8*)&qkv[qoff + s * 16 + h * 8];
    }

    f32x16 o_acc[2][2];
#pragma unroll
    for (int sub = 0; sub < 2; ++sub)
#pragma unroll
        for (int db = 0; db < 2; ++db)
#pragma unroll
            for (int i = 0; i < 16; ++i) o_acc[sub][db][i] = 0.f;
    float psum[2] = {0.f, 0.f};

    bf16* Ks = stage + w * 4096;        // [32][64]
    bf16* Vs = Ks + 2048;               // [64][32]

    // staging pointers for this wave's kv half
    const bf16* kp[4]; const bf16* vp[4];
    bf16* kd[4]; bf16* vd[4];
#pragma unroll
    for (int rdd = 0; rdd < 4; ++rdd) {
        int ciK = rdd * 64 + lane;
        int rowK = ciK >> 3, ccK = (ciK & 7) ^ (rowK & 7);
        kp[rdd] = &qkv[(size_t)(b * 2048 + w * 1024 + rowK) * 1536 + 512 + hd * 64 + ccK * 8];
        kd[rdd] = &Ks[ciK * 8];
        int ciV = rdd * 64 + lane;
        int rowV = ciV >> 2, ccV = (ciV & 3) ^ (rowV & 3);
        vp[rdd] = &vt[(size_t)(bh * 64 + rowV) * 2048 + w * 1024 + ccV * 8];
        vd[rdd] = &Vs[ciV * 8];
    }

    for (int it = 0; it < 32; ++it) {
#pragma unroll
        for (int rdd = 0; rdd < 4; ++rdd) {
            load_lds16(kp[rdd], kd[rdd]); kp[rdd] += (size_t)32 * 1536;
            load_lds16(vp[rdd], vd[rdd]); vp[rdd] += 32;
        }
        WAIT_VM0();     // wave-local drain; no barrier

        // K fragments (shared by both q-subtiles): A-row m = q (kv-local)
        bf16x8 kf[4];
#pragma unroll
        for (int s = 0; s < 4; ++s) {
            int cp = (s * 2 + h) ^ (q & 7);
            kf[s] = *(const bf16x8*)&Ks[q * 64 + cp * 8];
        }
        // V fragments (shared by both q-subtiles): A-row d = db*32+q
        bf16x8 vf[2][2];
#pragma unroll
        for (int kstep = 0; kstep < 2; ++kstep)
#pragma unroll
            for (int db = 0; db < 2; ++db) {
                int cp = (kstep * 2 + h) ^ (q & 3);
                vf[kstep][db] = *(const bf16x8*)&Vs[(db * 32 + q) * 32 + cp * 8];
            }

#pragma unroll
        for (int sub = 0; sub < 2; ++sub) {
            f32x16 sacc;
#pragma unroll
            for (int i = 0; i < 16; ++i) sacc[i] = 0.f;
#pragma unroll
            for (int s = 0; s < 4; ++s)
                sacc = MFMA32(kf[s], qf[sub][s], sacc);

            // P = exp2(S); psum; build PV B-frags
            bf16x4 pk[4];
            float ps = 0.f;
#pragma unroll
            for (int g8 = 0; g8 < 4; ++g8)
#pragma unroll
                for (int i = 0; i < 4; ++i) {
                    float p = EXP2(sacc[4 * g8 + i]);
                    ps += p;
                    pk[g8][i] = (bf16)p;
                }
            psum[sub] += ps;
            bf16x8 bfr0 = build_bfrag(pk[0], pk[1], h);
            bf16x8 bfr1 = build_bfrag(pk[2], pk[3], h);

            // O^T += V^T . P^T
#pragma unroll
            for (int db = 0; db < 2; ++db) {
                o_acc[sub][db] = MFMA32(vf[0][db], bfr0, o_acc[sub][db]);
                o_acc[sub][db] = MFMA32(vf[1][db], bfr1, o_acc[sub][db]);
            }
        }
    }

    // per-q l for this wave's kv half (sum both lane-halves)
    float l_own[2];
#pragma unroll
    for (int sub = 0; sub < 2; ++sub)
        l_own[sub] = psum[sub] + __shfl_xor(psum[sub], 32, 64);

    // ---- 2-way merge through LDS ----
    __syncthreads();
    float* Of = (float*)smemraw;               // [64 q][68]
    float* Lf = (float*)(smemraw + 17408);     // [64]

    if (w == 1) {
#pragma unroll
        for (int sub = 0; sub < 2; ++sub) {
#pragma unroll
            for (int db = 0; db < 2; ++db)
#pragma unroll
                for (int r = 0; r < 16; ++r) {
                    int d = db * 32 + (r & 3) + 8 * (r >> 2) + 4 * h;
                    Of[(sub * 32 + q) * 68 + d] = o_acc[sub][db][r];
                }
            if (h == 0) Lf[sub * 32 + q] = l_own[sub];
        }
    }
    __syncthreads();
    if (w == 0) {
#pragma unroll
        for (int sub = 0; sub < 2; ++sub) {
#pragma unroll
            for (int db = 0; db < 2; ++db)
#pragma unroll
                for (int r = 0; r < 16; ++r) {
                    int d = db * 32 + (r & 3) + 8 * (r >> 2) + 4 * h;
                    Of[(sub * 32 + q) * 68 + d] += o_acc[sub][db][r];
                }
            if (h == 0) Lf[sub * 32 + q] += l_own[sub];
        }
    }
    __syncthreads();

    // normalize + coalesced store: 128 threads, each 1 half-row (32 elems)
    {
        int row = t >> 1, half = t & 1;
        float linv = 1.f / Lf[row];
        const float* src = &Of[row * 68 + half * 32];
        bf16* dst = &out[(size_t)(b * 2048 + qb + row) * 512 + hd * 64 + half * 32];
#pragma unroll
        for (int i = 0; i < 4; ++i) {
            f32x4 a = *(const f32x4*)&src[i * 8];
            f32x4 c = *(const f32x4*)&src[i * 8 + 4];
            bf16x8 o8;
#pragma unroll
            for (int j = 0; j < 4; ++j) {
                o8[j] = (bf16)(a[j] * linv);
                o8[4 + j] = (bf16)(c[j] * linv);
            }
            *(bf16x8*)&dst[i * 8] = o8;
        }
    }
}

// ---------------------------------------------------------------------------
extern "C" void kernel_launch(void* const* d_in, const int* in_sizes, int n_in,
                              void* d_out, int out_size, void* d_ws, size_t ws_size,
                              hipStream_t stream) {
    const float* x     = (const float*)d_in[0];   // [4*2048][512] f32
    const float* w_qkv = (const float*)d_in[1];   // [512][1536]   f32
    const float* w_out = (const float*)d_in[2];   // [512][512]    f32
    const float* b_out = (const float*)d_in[3];   // [512]         f32
    float* out = (float*)d_out;                   // [4*2048][512] f32

    char* ws = (char*)d_ws;
    size_t off = 0;
    bf16* xb    = (bf16*)(ws + off); off += (size_t)8192 * 512 * 2;        // 8 MB
    bf16* wqkvT = (bf16*)(ws + off); off += (size_t)1536 * 512 * 2;        // 1.5 MB
    bf16* woutT = (bf16*)(ws + off); off += (size_t)512 * 512 * 2;         // 0.5 MB
    bf16* qkv   = (bf16*)(ws + off); off += (size_t)8192 * 1536 * 2;       // 24 MB
    bf16* vt    = (bf16*)(ws + off); off += (size_t)32 * 64 * 2048 * 2;    // 8 MB
    bf16* attn  = (bf16*)(ws + off);                                       // 8 MB

    f32_to_bf16_kernel<<<4096, 256, 0, stream>>>(x, xb, 8192 * 512);
    transpose_f2b<<<dim3(48, 16), 256, 0, stream>>>(w_qkv, wqkvT, 512, 1536);
    transpose_f2b<<<dim3(16, 16), 256, 0, stream>>>(w_out, woutT, 512, 512);
    // QKV GEMM, 128x128 tile (m97 shape), grid 768 = 3/CU
    gemm_bt_kernel<4, 1, bf16><<<dim3(12, 64), 256, 0, stream>>>(
        xb, wqkvT, nullptr, qkv, 8192, 1536, 512);
    transpose_v_kernel<<<dim3(64, 2, 32), 256, 0, stream>>>(qkv, vt);
    attn_kernel<<<dim3(32, 32), 128, 0, stream>>>(qkv, vt, attn);
    // out proj, BM=64, grid 512, +bias, f32 out
    gemm_bt_kernel<2, 2, float><<<dim3(4, 128), 256, 0, stream>>>(
        attn, woutT, b_out, out, 8192, 512, 512);
}

// Round 9
// 166.800 us; speedup vs baseline: 1.1603x; 1.0246x over previous
//
#include <hip/hip_runtime.h>

typedef __bf16 bf16;
typedef __bf16 bf16x8 __attribute__((ext_vector_type(8)));
typedef __bf16 bf16x4 __attribute__((ext_vector_type(4)));
typedef float f32x4 __attribute__((ext_vector_type(4)));
typedef float f32x16 __attribute__((ext_vector_type(16)));

#define MFMA16(a, b, c) __builtin_amdgcn_mfma_f32_16x16x32_bf16(a, b, c, 0, 0, 0)
#define MFMA32(a, b, c) __builtin_amdgcn_mfma_f32_32x32x16_bf16(a, b, c, 0, 0, 0)

// scale * log2(e) — folded into Q in GEMM1 epilogue (f32)
#define CS 0.18033688011112042f

// raw v_exp_f32 (r7-proven); args bounded so denormal fixup not needed
#if __has_builtin(__builtin_amdgcn_exp2f)
#define EXP2(x) __builtin_amdgcn_exp2f(x)
#else
#define EXP2(x) exp2f(x)
#endif

// wave-local waits (gfx9 encoding: vm[3:0]|exp[6:4]|lgkm[11:8]|vm[5:4]@15:14)
#define WAIT_VM0() __builtin_amdgcn_s_waitcnt(0x0F70)   // vmcnt(0), r8-proven
#define WAIT_VM8() __builtin_amdgcn_s_waitcnt(0x0F78)   // vmcnt(8)

// async global->LDS, 16B per lane; LDS dest must be lane-linear per wave.
__device__ __forceinline__ void load_lds16(const bf16* g, bf16* l) {
    __builtin_amdgcn_global_load_lds(
        (const __attribute__((address_space(1))) unsigned int*)g,
        (__attribute__((address_space(3))) unsigned int*)l, 16, 0, 0);
}

__device__ __forceinline__ bf16x4 shfl_xor32_b64(bf16x4 v) {
    union { bf16x4 b; int i[2]; } u;
    u.b = v;
    u.i[0] = __shfl_xor(u.i[0], 32, 64);
    u.i[1] = __shfl_xor(u.i[1], 32, 64);
    return u.b;
}

// PV B-operand fragment for one 16-kv window from C-layout P registers.
// Proven rounds 2-4, 6-8.
__device__ __forceinline__ bf16x8 build_bfrag(bf16x4 plo, bf16x4 phi, int h) {
    bf16x4 xlo = shfl_xor32_b64(plo);
    bf16x4 xhi = shfl_xor32_b64(phi);
    bf16x4 lo4 = h ? xhi : plo;
    bf16x4 hi4 = h ? phi : xlo;
    bf16x8 bb;
#pragma unroll
    for (int i = 0; i < 4; ++i) { bb[i] = lo4[i]; bb[4 + i] = hi4[i]; }
    return bb;
}

// ---------------------------------------------------------------------------
// f32 -> bf16 bulk convert (n divisible by 4).
// ---------------------------------------------------------------------------
__global__ __launch_bounds__(256) void f32_to_bf16_kernel(const float* __restrict__ in,
                                                          bf16* __restrict__ out, int n) {
    int i = (blockIdx.x * 256 + threadIdx.x) * 4;
    if (i < n) {
        float4 v = *(const float4*)&in[i];
        bf16x4 o = {(bf16)v.x, (bf16)v.y, (bf16)v.z, (bf16)v.w};
        *(bf16x4*)&out[i] = o;
    }
}

// ---------------------------------------------------------------------------
// f32 [R][C] -> bf16 [C][R] transpose, 32x32 LDS tiles.
// ---------------------------------------------------------------------------
__global__ __launch_bounds__(256) void transpose_f2b(const float* __restrict__ in,
                                                     bf16* __restrict__ out,
                                                     int R, int C) {
    __shared__ float tile[32][33];
    int tx = threadIdx.x & 31, ty = threadIdx.x >> 5;
    int c0 = blockIdx.x * 32, r0 = blockIdx.y * 32;
#pragma unroll
    for (int i = ty; i < 32; i += 8)
        tile[i][tx] = in[(size_t)(r0 + i) * C + c0 + tx];
    __syncthreads();
#pragma unroll
    for (int i = ty; i < 32; i += 8)
        out[(size_t)(c0 + i) * R + r0 + tx] = (bf16)tile[tx][i];
}

// ---------------------------------------------------------------------------
// V slice of qkv (bf16) -> vt[bh][64][2048]  (vt[bh][d][n] = V[b][n][h][d])
// ---------------------------------------------------------------------------
__global__ __launch_bounds__(256) void transpose_v_kernel(const bf16* __restrict__ qkv,
                                                          bf16* __restrict__ vt) {
    __shared__ bf16 tile[32][33];
    int tx = threadIdx.x & 31, ty = threadIdx.x >> 5;
    int bh = blockIdx.z, b = bh >> 3, h = bh & 7;
    int n0 = blockIdx.x * 32, d0 = blockIdx.y * 32;
#pragma unroll
    for (int i = ty; i < 32; i += 8)
        tile[i][tx] = qkv[(size_t)(b * 2048 + n0 + i) * 1536 + 1024 + h * 64 + d0 + tx];
    __syncthreads();
#pragma unroll
    for (int i = ty; i < 32; i += 8)
        vt[(size_t)(bh * 64 + d0 + i) * 2048 + n0 + tx] = tile[tx][i];
}

// ---------------------------------------------------------------------------
// C[M][N] = A[M][K] @ Bt[N][K]^T, bf16 in, fp32 acc. BM=MT*32, BN=128, BK=64.
// MODE 1: cols<512 scaled by CS (Q pre-scale), bf16 out. MODE 2: +bias, f32.
// ---------------------------------------------------------------------------
template <int MT, int MODE, typename OutT>
__global__ __launch_bounds__(256, (MT == 4) ? 2 : 4)
void gemm_bt_kernel(const bf16* __restrict__ A,
                    const bf16* __restrict__ Bt,
                    const float* __restrict__ bias,
                    OutT* __restrict__ C,
                    int M, int N, int K) {
    const int BM = MT * 32;
    __shared__ bf16 As[BM * 64];
    __shared__ bf16 Bs[128 * 64];
    int t = threadIdx.x;
    int lane = t & 63, w = t >> 6;
    int wr = w >> 1, wc = w & 1;
    int quad = lane >> 4, r16 = lane & 15;
    int m0 = blockIdx.y * BM, n0 = blockIdx.x * 128;

    const f32x4 fzero = {0.f, 0.f, 0.f, 0.f};
    f32x4 acc[MT][4];
#pragma unroll
    for (int i = 0; i < MT; ++i)
#pragma unroll
        for (int j = 0; j < 4; ++j) acc[i][j] = fzero;

    const bf16* ap[MT]; bf16* ad[MT];
    const bf16* bp[4];  bf16* bd[4];
#pragma unroll
    for (int i = 0; i < MT; ++i) {
        int ci = i * 256 + t;
        int row = ci >> 3, cp = ci & 7, cc = cp ^ (row & 7);
        ap[i] = &A[(size_t)(m0 + row) * K + cc * 8];
        ad[i] = &As[ci * 8];
    }
#pragma unroll
    for (int i = 0; i < 4; ++i) {
        int ci = i * 256 + t;
        int row = ci >> 3, cp = ci & 7, cc = cp ^ (row & 7);
        bp[i] = &Bt[(size_t)(n0 + row) * K + cc * 8];
        bd[i] = &Bs[ci * 8];
    }

    for (int k0 = 0; k0 < K; k0 += 64) {
        __syncthreads();
#pragma unroll
        for (int i = 0; i < MT; ++i) { load_lds16(ap[i], ad[i]); ap[i] += 64; }
#pragma unroll
        for (int i = 0; i < 4; ++i) { load_lds16(bp[i], bd[i]); bp[i] += 64; }
        __syncthreads();
#pragma unroll
        for (int ks = 0; ks < 2; ++ks) {
            bf16x8 af[MT], bfr[4];
            int cp = (ks * 4 + quad) ^ (r16 & 7);
#pragma unroll
            for (int mt = 0; mt < MT; ++mt)
                af[mt] = *(const bf16x8*)&As[(wr * (BM / 2) + mt * 16 + r16) * 64 + cp * 8];
#pragma unroll
            for (int nt = 0; nt < 4; ++nt)
                bfr[nt] = *(const bf16x8*)&Bs[(wc * 64 + nt * 16 + r16) * 64 + cp * 8];
#pragma unroll
            for (int mt = 0; mt < MT; ++mt)
#pragma unroll
                for (int nt = 0; nt < 4; ++nt)
                    acc[mt][nt] = MFMA16(af[mt], bfr[nt], acc[mt][nt]);
        }
    }
#pragma unroll
    for (int mt = 0; mt < MT; ++mt)
#pragma unroll
        for (int nt = 0; nt < 4; ++nt)
#pragma unroll
            for (int r = 0; r < 4; ++r) {
                int row = m0 + wr * (BM / 2) + mt * 16 + quad * 4 + r;
                int col = n0 + wc * 64 + nt * 16 + r16;
                float v = acc[mt][nt][r];
                if (MODE == 1 && n0 < 512) v *= CS;
                if (MODE == 2) v += bias[col];
                C[(size_t)row * N + col] = (OutT)v;
            }
}

// ---------------------------------------------------------------------------
// Flash attention v4: barrier-free per-wave streaming + SW-pipelined staging.
// Block = 2 waves; wave w owns kv half, 32 iters of kv-32, DOUBLE-buffered
// private 8KB tiles. Iter it: issue tile it+1 into other buf, then
// s_waitcnt vmcnt(8) — waits only tile it's 8 loads, tile it+1 stays in
// flight behind compute (AITER-style, possible because no barriers).
// No-max softmax (Q pre-scaled by CS); l via f32 psum; 2-way merge via LDS.
// ---------------------------------------------------------------------------
__global__ __launch_bounds__(128, 2) void attn_kernel(const bf16* __restrict__ qkv,
                                                      const bf16* __restrict__ vt,
                                                      bf16* __restrict__ out) {
    __shared__ __align__(16) char smemraw[32768];
    bf16* stage = (bf16*)smemraw;       // [2 waves][2 bufs][4096 elems]

    int t = threadIdx.x;
    int lane = t & 63, w = t >> 6;      // w in {0,1}
    int h = lane >> 5, q = lane & 31;
    int bh = blockIdx.y, b = bh >> 3, hd = bh & 7;
    int qb = blockIdx.x * 64;

    // Q fragments for both subtiles: lane holds Q[qb+sub*32+q][s*16+h*8+j]
    bf16x8 qf[2][4];
#pragma unroll
    for (int sub = 0; sub < 2; ++sub) {
        size_t qoff = (size_t)(b * 2048 + qb + sub * 32 + q) * 1536 + hd * 64;
#pragma unroll
        for (int s = 0; s < 4; ++s)
            qf[sub][s] = *(const bf16x8*)&qkv[qoff + s * 16 + h * 8];
    }

    f32x16 o_acc[2][2];
#pragma unroll
    for (int sub = 0; sub < 2; ++sub)
#pragma unroll
        for (int db = 0; db < 2; ++db)
#pragma unroll
            for (int i = 0; i < 16; ++i) o_acc[sub][db][i] = 0.f;
    float psum[2] = {0.f, 0.f};

    bf16* base = stage + w * 8192;      // this wave's two buffers

    // staging pointers (advance by constant stride) + LDS offsets in-buffer
    const bf16* kp[4]; const bf16* vp[4];
    int kdo[4], vdo[4];
#pragma unroll
    for (int rdd = 0; rdd < 4; ++rdd) {
        int ciK = rdd * 64 + lane;
        int rowK = ciK >> 3, ccK = (ciK & 7) ^ (rowK & 7);
        kp[rdd] = &qkv[(size_t)(b * 2048 + w * 1024 + rowK) * 1536 + 512 + hd * 64 + ccK * 8];
        kdo[rdd] = ciK * 8;
        int ciV = rdd * 64 + lane;
        int rowV = ciV >> 2, ccV = (ciV & 3) ^ (rowV & 3);
        vp[rdd] = &vt[(size_t)(bh * 64 + rowV) * 2048 + w * 1024 + ccV * 8];
        vdo[rdd] = 2048 + ciV * 8;
    }

    // prologue: stage tile 0 into buf 0
#pragma unroll
    for (int rdd = 0; rdd < 4; ++rdd) {
        load_lds16(kp[rdd], base + kdo[rdd]);  kp[rdd] += (size_t)32 * 1536;
        load_lds16(vp[rdd], base + vdo[rdd]);  vp[rdd] += 32;
    }

    for (int it = 0; it < 32; ++it) {
        const bf16* Ks = base + (it & 1) * 4096;   // [32][64]
        const bf16* Vs = Ks + 2048;                // [64][32]
        if (it < 31) {
            bf16* nb = base + ((it + 1) & 1) * 4096;
#pragma unroll
            for (int rdd = 0; rdd < 4; ++rdd) {
                load_lds16(kp[rdd], nb + kdo[rdd]);  kp[rdd] += (size_t)32 * 1536;
                load_lds16(vp[rdd], nb + vdo[rdd]);  vp[rdd] += 32;
            }
            WAIT_VM8();    // tile `it` resident; tile it+1 still in flight
        } else {
            WAIT_VM0();    // final tile resident
        }

        // K fragments (shared by both q-subtiles): A-row m = q (kv-local)
        bf16x8 kf[4];
#pragma unroll
        for (int s = 0; s < 4; ++s) {
            int cp = (s * 2 + h) ^ (q & 7);
            kf[s] = *(const bf16x8*)&Ks[q * 64 + cp * 8];
        }
        // V fragments (shared by both q-subtiles): A-row d = db*32+q
        bf16x8 vf[2][2];
#pragma unroll
        for (int kstep = 0; kstep < 2; ++kstep)
#pragma unroll
            for (int db = 0; db < 2; ++db) {
                int cp = (kstep * 2 + h) ^ (q & 3);
                vf[kstep][db] = *(const bf16x8*)&Vs[(db * 32 + q) * 32 + cp * 8];
            }

#pragma unroll
        for (int sub = 0; sub < 2; ++sub) {
            f32x16 sacc;
#pragma unroll
            for (int i = 0; i < 16; ++i) sacc[i] = 0.f;
#pragma unroll
            for (int s = 0; s < 4; ++s)
                sacc = MFMA32(kf[s], qf[sub][s], sacc);

            // P = exp2(S); psum; build PV B-frags
            bf16x4 pk[4];
            float ps = 0.f;
#pragma unroll
            for (int g8 = 0; g8 < 4; ++g8)
#pragma unroll
                for (int i = 0; i < 4; ++i) {
                    float p = EXP2(sacc[4 * g8 + i]);
                    ps += p;
                    pk[g8][i] = (bf16)p;
                }
            psum[sub] += ps;
            bf16x8 bfr0 = build_bfrag(pk[0], pk[1], h);
            bf16x8 bfr1 = build_bfrag(pk[2], pk[3], h);

            // O^T += V^T . P^T
#pragma unroll
            for (int db = 0; db < 2; ++db) {
                o_acc[sub][db] = MFMA32(vf[0][db], bfr0, o_acc[sub][db]);
                o_acc[sub][db] = MFMA32(vf[1][db], bfr1, o_acc[sub][db]);
            }
        }
    }

    // per-q l for this wave's kv half (sum both lane-halves)
    float l_own[2];
#pragma unroll
    for (int sub = 0; sub < 2; ++sub)
        l_own[sub] = psum[sub] + __shfl_xor(psum[sub], 32, 64);

    // ---- 2-way merge through LDS (overlays stage buffers; barriered) ----
    __syncthreads();
    float* Of = (float*)smemraw;               // [64 q][68]
    float* Lf = (float*)(smemraw + 17408);     // [64]

    if (w == 1) {
#pragma unroll
        for (int sub = 0; sub < 2; ++sub) {
#pragma unroll
            for (int db = 0; db < 2; ++db)
#pragma unroll
                for (int r = 0; r < 16; ++r) {
                    int d = db * 32 + (r & 3) + 8 * (r >> 2) + 4 * h;
                    Of[(sub * 32 + q) * 68 + d] = o_acc[sub][db][r];
                }
            if (h == 0) Lf[sub * 32 + q] = l_own[sub];
        }
    }
    __syncthreads();
    if (w == 0) {
#pragma unroll
        for (int sub = 0; sub < 2; ++sub) {
#pragma unroll
            for (int db = 0; db < 2; ++db)
#pragma unroll
                for (int r = 0; r < 16; ++r) {
                    int d = db * 32 + (r & 3) + 8 * (r >> 2) + 4 * h;
                    Of[(sub * 32 + q) * 68 + d] += o_acc[sub][db][r];
                }
            if (h == 0) Lf[sub * 32 + q] += l_own[sub];
        }
    }
    __syncthreads();

    // normalize + coalesced store: 128 threads, each 1 half-row (32 elems)
    {
        int row = t >> 1, half = t & 1;
        float linv = 1.f / Lf[row];
        const float* src = &Of[row * 68 + half * 32];
        bf16* dst = &out[(size_t)(b * 2048 + qb + row) * 512 + hd * 64 + half * 32];
#pragma unroll
        for (int i = 0; i < 4; ++i) {
            f32x4 a = *(const f32x4*)&src[i * 8];
            f32x4 c = *(const f32x4*)&src[i * 8 + 4];
            bf16x8 o8;
#pragma unroll
            for (int j = 0; j < 4; ++j) {
                o8[j] = (bf16)(a[j] * linv);
                o8[4 + j] = (bf16)(c[j] * linv);
            }
            *(bf16x8*)&dst[i * 8] = o8;
        }
    }
}

// ---------------------------------------------------------------------------
extern "C" void kernel_launch(void* const* d_in, const int* in_sizes, int n_in,
                              void* d_out, int out_size, void* d_ws, size_t ws_size,
                              hipStream_t stream) {
    const float* x     = (const float*)d_in[0];   // [4*2048][512] f32
    const float* w_qkv = (const float*)d_in[1];   // [512][1536]   f32
    const float* w_out = (const float*)d_in[2];   // [512][512]    f32
    const float* b_out = (const float*)d_in[3];   // [512]         f32
    float* out = (float*)d_out;                   // [4*2048][512] f32

    char* ws = (char*)d_ws;
    size_t off = 0;
    bf16* xb    = (bf16*)(ws + off); off += (size_t)8192 * 512 * 2;        // 8 MB
    bf16* wqkvT = (bf16*)(ws + off); off += (size_t)1536 * 512 * 2;        // 1.5 MB
    bf16* woutT = (bf16*)(ws + off); off += (size_t)512 * 512 * 2;         // 0.5 MB
    bf16* qkv   = (bf16*)(ws + off); off += (size_t)8192 * 1536 * 2;       // 24 MB
    bf16* vt    = (bf16*)(ws + off); off += (size_t)32 * 64 * 2048 * 2;    // 8 MB
    bf16* attn  = (bf16*)(ws + off);                                       // 8 MB

    f32_to_bf16_kernel<<<4096, 256, 0, stream>>>(x, xb, 8192 * 512);
    transpose_f2b<<<dim3(48, 16), 256, 0, stream>>>(w_qkv, wqkvT, 512, 1536);
    transpose_f2b<<<dim3(16, 16), 256, 0, stream>>>(w_out, woutT, 512, 512);
    // QKV GEMM, 128x128 tile, grid 768 = 3/CU
    gemm_bt_kernel<4, 1, bf16><<<dim3(12, 64), 256, 0, stream>>>(
        xb, wqkvT, nullptr, qkv, 8192, 1536, 512);
    transpose_v_kernel<<<dim3(64, 2, 32), 256, 0, stream>>>(qkv, vt);
    attn_kernel<<<dim3(32, 32), 128, 0, stream>>>(qkv, vt, attn);
    // out proj, BM=64, grid 512, +bias, f32 out
    gemm_bt_kernel<2, 2, float><<<dim3(4, 128), 256, 0, stream>>>(
        attn, woutT, b_out, out, 8192, 512, 512);
}